// Round 3
// baseline (151.658 us; speedup 1.0000x reference)
//
#include <hip/hip_runtime.h>
#include <hip/hip_bf16.h>
#include <stdint.h>

#define UNITS 1024
#define IDIM  512
#define BATCH 2048
#define KTOT  1536   // UNITS + IDIM
#define NGATE 4096   // 4*UNITS
#define BK    64
#define NITER (KTOT / BK)   // 24

typedef short bf16x8 __attribute__((ext_vector_type(8)));   // 8 bf16 = 4 VGPRs
typedef float f32x4  __attribute__((ext_vector_type(4)));

#define AS3(p) ((__attribute__((address_space(3))) void*)(p))
#define AS1(p) ((const __attribute__((address_space(1))) void*)(p))

union P8 { bf16x8 v; __hip_bfloat16 e[8]; };

// ---------------------------------------------------------------------------
// prep: blocks [0,1536) cast-concat A = bf16(concat[h,x]); blocks [1536,4608)
// transpose W fp32 [1536][4096] -> Wt bf16 [4096][1536] (k-contiguous rows).
// ---------------------------------------------------------------------------
#define NBLK_A 1536
#define NBLK_T 3072

__global__ __launch_bounds__(256) void prep(
    const float* __restrict__ x, const float* __restrict__ h,
    const float* __restrict__ W,
    __hip_bfloat16* __restrict__ A, __hip_bfloat16* __restrict__ Wt) {
  __shared__ float tile[32][65];
  const int tid = threadIdx.x;
  if (blockIdx.x < NBLK_A) {
    const int id = blockIdx.x * 256 + tid;
    const int r = id / (KTOT / 8);
    const int k = (id % (KTOT / 8)) * 8;
    const float* src = (k < UNITS) ? h + (size_t)r * UNITS + k
                                   : x + (size_t)r * IDIM + (k - UNITS);
    const float4 v0 = ((const float4*)src)[0];
    const float4 v1 = ((const float4*)src)[1];
    P8 o;
    o.e[0] = __float2bfloat16(v0.x); o.e[1] = __float2bfloat16(v0.y);
    o.e[2] = __float2bfloat16(v0.z); o.e[3] = __float2bfloat16(v0.w);
    o.e[4] = __float2bfloat16(v1.x); o.e[5] = __float2bfloat16(v1.y);
    o.e[6] = __float2bfloat16(v1.z); o.e[7] = __float2bfloat16(v1.w);
    *(bf16x8*)(A + (size_t)r * KTOT + k) = o.v;
  } else {
    const int b  = blockIdx.x - NBLK_A;   // 0..3071
    const int kb = b >> 7;                // 0..23
    const int nb = b & 127;               // 0..127
    const int k0 = kb * 64, n0 = nb * 32;
    const int n4 = (tid & 7) * 4;
    const int kk = tid >> 3;              // 0..31
#pragma unroll
    for (int rr = 0; rr < 64; rr += 32) {
      const float4 v = *(const float4*)(W + (size_t)(k0 + kk + rr) * NGATE + n0 + n4);
      tile[n4 + 0][kk + rr] = v.x; tile[n4 + 1][kk + rr] = v.y;
      tile[n4 + 2][kk + rr] = v.z; tile[n4 + 3][kk + rr] = v.w;
    }
    __syncthreads();
    const int n  = tid >> 3;
    const int k8 = (tid & 7) * 8;
    P8 o;
#pragma unroll
    for (int j = 0; j < 8; ++j) o.e[j] = __float2bfloat16(tile[n][k8 + j]);
    *(bf16x8*)(Wt + (size_t)(n0 + n) * KTOT + k0 + k8) = o.v;
  }
}

// ---------------------------------------------------------------------------
// GEMM + fused LSTM. Grid 512 (2 blocks/CU), block 256 threads = 4 waves
// tiling 2 (row) x 2 (unit): wave = 64 rows x 16 units x 4 gates, acc[4][4]
// 16x16 tiles (64 VGPR). All 4 gates live in-lane -> register-local epilogue.
//
// A: LDS double-buffered (2 x 16 KB), global_load_lds width=16, XOR-swizzled
//    chunks (2 lanes/bank, free). Prefetch iter k+1 BEFORE computing iter k,
//    so the compiler's vmcnt(0) drain at the barrier lands after compute.
// B: NEVER staged in LDS -- global_load_dwordx4 from Wt, register
//    double-buffered one K-iter ahead. XCD swizzle (ub = bi&31, XCD = ub%8)
//    keeps each XCD's Wt working set at 1.6 MB -> L2-resident; the wu-pair
//    of waves reads identical fragments -> L1 dedup.
// Per CU per iter: LDS ~96 KB (vs 288 KB in R2), L2 ~64 KB, MFMA 310 cyc.
// ---------------------------------------------------------------------------
__global__ __launch_bounds__(256, 2) void lstm_gemm(
    const __hip_bfloat16* __restrict__ A,
    const __hip_bfloat16* __restrict__ Wt,
    const float* __restrict__ c_tm1,
    float* __restrict__ out) {
  __shared__ __attribute__((aligned(128))) char lds[2 * 16384];

  const int tid  = threadIdx.x;
  const int w    = tid >> 6;     // wave 0..3 (uniform)
  const int lane = tid & 63;
  const int quad = lane >> 4;
  const int m16  = lane & 15;
  const int wr   = w >> 1;       // row half (0,1)
  const int wu   = w & 1;        // unit half (0,1)

  const int mb = blockIdx.x >> 5;   // 0..15
  const int ub = blockIdx.x & 31;   // 0..31  -> XCD = ub % 8
  const int m0 = mb * 128;
  const int u0 = ub * 32;

  // A staging: 1024 chunks (16 B) per buffer / 256 threads = 4 per thread.
  const __hip_bfloat16* aptr[4];
  int adst[4];
#pragma unroll
  for (int s = 0; s < 4; ++s) {
    const int q   = s * 4 + w;         // wave-uniform 0..15
    const int ci  = q * 64 + lane;     // chunk 0..1023
    const int row = ci >> 3;           // 0..127
    const int k8  = (ci & 7) ^ (row & 7);
    aptr[s] = A + (size_t)(m0 + row) * KTOT + k8 * 8;
    adst[s] = q * 1024;                // wave-uniform LDS offset
  }

  // B fragment base pointers, one per gate; lane covers unit col m16,
  // k-offset quad*8 (16 contiguous bytes per load).
  const __hip_bfloat16* bp[4];
#pragma unroll
  for (int g = 0; g < 4; ++g)
    bp[g] = Wt + (size_t)((g << 10) + u0 + wu * 16 + m16) * KTOT + quad * 8;

  f32x4 acc[4][4];
#pragma unroll
  for (int i = 0; i < 4; ++i)
#pragma unroll
    for (int g = 0; g < 4; ++g) {
      f32x4 z = {0.f, 0.f, 0.f, 0.f};
      acc[i][g] = z;
    }

  bf16x8 breg[2][4][2];   // [parity][gate][t]

  // prologue: stage iter 0
#pragma unroll
  for (int s = 0; s < 4; ++s)
    __builtin_amdgcn_global_load_lds(AS1(aptr[s]), AS3(lds + adst[s]), 16, 0, 0);
#pragma unroll
  for (int g = 0; g < 4; ++g)
#pragma unroll
    for (int t = 0; t < 2; ++t)
      breg[0][g][t] = *(const bf16x8*)(bp[g] + t * 32);
  __syncthreads();

#pragma unroll 2
  for (int it = 0; it < NITER; ++it) {
    const int cur = it & 1;
    const int nxt = cur ^ 1;
    // prefetch iter it+1 (A -> other LDS buffer, B -> other reg set)
    if (it < NITER - 1) {
      const int koff = (it + 1) * BK;
#pragma unroll
      for (int s = 0; s < 4; ++s)
        __builtin_amdgcn_global_load_lds(AS1(aptr[s] + koff),
                                         AS3(lds + nxt * 16384 + adst[s]), 16, 0, 0);
#pragma unroll
      for (int g = 0; g < 4; ++g)
#pragma unroll
        for (int t = 0; t < 2; ++t)
          breg[nxt][g][t] = *(const bf16x8*)(bp[g] + koff + t * 32);
    }
    // compute iter it from buffer `cur`
#pragma unroll
    for (int t = 0; t < 2; ++t) {
      bf16x8 a[4];
#pragma unroll
      for (int i = 0; i < 4; ++i) {
        const int row  = wr * 64 + i * 16 + m16;
        const int slot = (t * 4 + quad) ^ (row & 7);
        a[i] = *(const bf16x8*)(lds + cur * 16384 + (row * 8 + slot) * 16);
      }
#pragma unroll
      for (int g = 0; g < 4; ++g)
#pragma unroll
        for (int i = 0; i < 4; ++i)
          acc[i][g] = __builtin_amdgcn_mfma_f32_16x16x32_bf16(a[i], breg[cur][g][t],
                                                              acc[i][g], 0, 0, 0);
    }
    __syncthreads();   // waits prefetch (vmcnt) + read-done before overwrite
  }

  // fused LSTM epilogue -- all 4 gates in-lane
  const int u = u0 + wu * 16 + m16;
#pragma unroll
  for (int i = 0; i < 4; ++i)
#pragma unroll
    for (int reg = 0; reg < 4; ++reg) {
      const int r = m0 + wr * 64 + i * 16 + quad * 4 + reg;
      const float z0 = acc[i][0][reg];   // gate i
      const float z1 = acc[i][1][reg];   // gate f
      const float z2 = acc[i][2][reg];   // c_tilde
      const float z3 = acc[i][3][reg];   // gate o
      const float ig = 1.f / (1.f + __expf(-z0));
      const float fg = 1.f / (1.f + __expf(-z1));
      const float ct = 1.f - 2.f / (__expf(2.f * z2) + 1.f);   // tanh, inf-safe
      const float og = 1.f / (1.f + __expf(-z3));
      const float cc = fg * c_tm1[(size_t)r * UNITS + u] + ig * ct;
      const float hh = og * (1.f - 2.f / (__expf(2.f * cc) + 1.f));
      out[(size_t)r * UNITS + u] = hh;
      out[(size_t)BATCH * UNITS + (size_t)r * UNITS + u] = cc;
    }
}

// ---------------------------------------------------------------------------
// Fallback (only if d_ws too small): naive fp32, correct but slow.
// ---------------------------------------------------------------------------
__global__ __launch_bounds__(256) void lstm_naive(
    const float* __restrict__ x, const float* __restrict__ h,
    const float* __restrict__ c_tm1, const float* __restrict__ W,
    float* __restrict__ out) {
  int idx = blockIdx.x * 256 + threadIdx.x;
  int r = idx / UNITS;
  int u = idx % UNITS;
  float z[4] = {0.f, 0.f, 0.f, 0.f};
  for (int k = 0; k < KTOT; ++k) {
    float a = (k < UNITS) ? h[(size_t)r * UNITS + k] : x[(size_t)r * IDIM + k - UNITS];
#pragma unroll
    for (int g = 0; g < 4; ++g)
      z[g] += a * W[(size_t)k * NGATE + g * UNITS + u];
  }
  float ig = 1.f / (1.f + __expf(-z[0]));
  float fg = 1.f / (1.f + __expf(-z[1]));
  float ct = 1.f - 2.f / (__expf(2.f * z[2]) + 1.f);
  float og = 1.f / (1.f + __expf(-z[3]));
  float cc = fg * c_tm1[(size_t)r * UNITS + u] + ig * ct;
  float hh = og * (1.f - 2.f / (__expf(2.f * cc) + 1.f));
  out[(size_t)r * UNITS + u] = hh;
  out[(size_t)BATCH * UNITS + (size_t)r * UNITS + u] = cc;
}

extern "C" void kernel_launch(void* const* d_in, const int* in_sizes, int n_in,
                              void* d_out, int out_size, void* d_ws, size_t ws_size,
                              hipStream_t stream) {
  const float* x = (const float*)d_in[0];   // [2048][512]
  const float* h = (const float*)d_in[1];   // [2048][1024]
  const float* c = (const float*)d_in[2];   // [2048][1024]
  const float* W = (const float*)d_in[3];   // [1536][4096]
  float* out = (float*)d_out;               // h then c, 2 x [2048][1024]

  const size_t needA  = (size_t)BATCH * KTOT * sizeof(__hip_bfloat16);  // 6.29 MB
  const size_t needWt = (size_t)NGATE * KTOT * sizeof(__hip_bfloat16);  // 12.58 MB
  if (ws_size < needA + needWt) {
    hipLaunchKernelGGL(lstm_naive, dim3((BATCH * UNITS) / 256), dim3(256), 0, stream,
                       x, h, c, W, out);
    return;
  }

  __hip_bfloat16* A  = (__hip_bfloat16*)d_ws;
  __hip_bfloat16* Wt = (__hip_bfloat16*)((char*)d_ws + needA);

  hipLaunchKernelGGL(prep, dim3(NBLK_A + NBLK_T), dim3(256), 0, stream, x, h, W, A, Wt);
  hipLaunchKernelGGL(lstm_gemm, dim3(512), dim3(256), 0, stream, A, Wt, c, out);
}

// Round 4
// 121.865 us; speedup vs baseline: 1.2445x; 1.2445x over previous
//
#include <hip/hip_runtime.h>
#include <hip/hip_bf16.h>
#include <stdint.h>

#define UNITS 1024
#define IDIM  512
#define BATCH 2048
#define KTOT  1536   // UNITS + IDIM
#define NGATE 4096   // 4*UNITS
#define BK    64
#define NITER (KTOT / BK)   // 24

typedef short bf16x8 __attribute__((ext_vector_type(8)));   // 8 bf16 = 4 VGPRs
typedef float f32x4  __attribute__((ext_vector_type(4)));

#define AS3(p) ((__attribute__((address_space(3))) void*)(p))
#define AS1(p) ((const __attribute__((address_space(1))) void*)(p))

union P8 { bf16x8 v; __hip_bfloat16 e[8]; };

// ---------------------------------------------------------------------------
// prep: blocks [0,1536) cast-concat A = bf16(concat[h,x]); blocks [1536,4608)
// transpose W fp32 [1536][4096] -> Wt bf16 [4096][1536] (k-contiguous rows).
// ---------------------------------------------------------------------------
#define NBLK_A 1536
#define NBLK_T 3072

__global__ __launch_bounds__(256) void prep(
    const float* __restrict__ x, const float* __restrict__ h,
    const float* __restrict__ W,
    __hip_bfloat16* __restrict__ A, __hip_bfloat16* __restrict__ Wt) {
  __shared__ float tile[32][65];
  const int tid = threadIdx.x;
  if (blockIdx.x < NBLK_A) {
    const int id = blockIdx.x * 256 + tid;
    const int r = id / (KTOT / 8);
    const int k = (id % (KTOT / 8)) * 8;
    const float* src = (k < UNITS) ? h + (size_t)r * UNITS + k
                                   : x + (size_t)r * IDIM + (k - UNITS);
    const float4 v0 = ((const float4*)src)[0];
    const float4 v1 = ((const float4*)src)[1];
    P8 o;
    o.e[0] = __float2bfloat16(v0.x); o.e[1] = __float2bfloat16(v0.y);
    o.e[2] = __float2bfloat16(v0.z); o.e[3] = __float2bfloat16(v0.w);
    o.e[4] = __float2bfloat16(v1.x); o.e[5] = __float2bfloat16(v1.y);
    o.e[6] = __float2bfloat16(v1.z); o.e[7] = __float2bfloat16(v1.w);
    *(bf16x8*)(A + (size_t)r * KTOT + k) = o.v;
  } else {
    const int b  = blockIdx.x - NBLK_A;   // 0..3071
    const int kb = b >> 7;                // 0..23
    const int nb = b & 127;               // 0..127
    const int k0 = kb * 64, n0 = nb * 32;
    const int n4 = (tid & 7) * 4;
    const int kk = tid >> 3;              // 0..31
#pragma unroll
    for (int rr = 0; rr < 64; rr += 32) {
      const float4 v = *(const float4*)(W + (size_t)(k0 + kk + rr) * NGATE + n0 + n4);
      tile[n4 + 0][kk + rr] = v.x; tile[n4 + 1][kk + rr] = v.y;
      tile[n4 + 2][kk + rr] = v.z; tile[n4 + 3][kk + rr] = v.w;
    }
    __syncthreads();
    const int n  = tid >> 3;
    const int k8 = (tid & 7) * 8;
    P8 o;
#pragma unroll
    for (int j = 0; j < 8; ++j) o.e[j] = __float2bfloat16(tile[n][k8 + j]);
    *(bf16x8*)(Wt + (size_t)(n0 + n) * KTOT + k0 + k8) = o.v;
  }
}

// ---------------------------------------------------------------------------
// GEMM + fused LSTM. Grid 512 (2 blocks/CU). Block tile: 128 rows x 32 units
// (x4 gates = 128 virtual cols). 4 waves tile 2x2: wave = 64 rows x 16 units
// x 4 gates -> acc[4][4] (64 VGPR), r=c=4 => 32.8 kFLOP per ds_read_b128
// (1.5x better than R2's r=2,c=4; this is the LDS-read-bound lever).
// All 4 gates in-lane -> register-local LSTM epilogue.
//
// A AND B both double-buffered in LDS (4 x 16 KB = 64 KB): prefetch iter k+1
// via global_load_lds(width=16) BEFORE computing iter k, one barrier/iter --
// the vmcnt(0) drain at the barrier lands after ~2x(8 ds_read + 16 MFMA) of
// compute. (R3 lesson: per-lane global B = 16-line gather per load, latency-
// bound at 14% MfmaUtil. B belongs in LDS.)
// 16B chunks XOR-swizzled chunk(row,k8)=row*8+(k8^(row&7)) -> 2 lanes/bank
// (free, m136); measured 0 conflicts in R1/R2.
// XCD: XCD = bi%8 = ub%8 -> 4 co-XCD blocks share each ub B-slice (1.6 MB,
// L2-resident); same-mb blocks on an XCD share A tiles.
// ---------------------------------------------------------------------------
__global__ __launch_bounds__(256, 2) void lstm_gemm(
    const __hip_bfloat16* __restrict__ A,
    const __hip_bfloat16* __restrict__ Wt,
    const float* __restrict__ c_tm1,
    float* __restrict__ out) {
  __shared__ __attribute__((aligned(128))) char lds[4 * 16384];  // A0 A1 B0 B1

  const int tid  = threadIdx.x;
  const int w    = tid >> 6;     // wave 0..3 (uniform)
  const int lane = tid & 63;
  const int quad = lane >> 4;
  const int m16  = lane & 15;
  const int wr   = w >> 1;       // row half (0,1)
  const int wu   = w & 1;        // unit half (0,1)

  const int mb = blockIdx.x >> 5;   // 0..15
  const int ub = blockIdx.x & 31;   // 0..31  (XCD = ub % 8)
  const int m0 = mb * 128;
  const int u0 = ub * 32;

  // Staging: 2048 16B chunks per iter (A 1024 + B 1024) / 256 thr = 8 each.
  const __hip_bfloat16* ptr[8];
  int dst[8];
#pragma unroll
  for (int s = 0; s < 8; ++s) {
    const int q  = s * 4 + w;        // wave-uniform 0..31
    const int ci = (q & 15) * 64 + lane;   // chunk 0..1023 within tile
    const int row = ci >> 3;               // 0..127
    const int k8  = (ci & 7) ^ (row & 7);  // source-side swizzle
    if (q < 16) {   // A tile
      ptr[s] = A + (size_t)(m0 + row) * KTOT + k8 * 8;
      dst[s] = q * 1024;                   // within A buffer
    } else {        // B tile: virtual col row -> Wt row
      const int wrow = ((row >> 5) << 10) + u0 + (row & 31);
      ptr[s] = Wt + (size_t)wrow * KTOT + k8 * 8;
      dst[s] = 32768 + (q - 16) * 1024;    // within B buffer 0
    }
  }

  f32x4 acc[4][4];
#pragma unroll
  for (int i = 0; i < 4; ++i)
#pragma unroll
    for (int g = 0; g < 4; ++g) {
      f32x4 z = {0.f, 0.f, 0.f, 0.f};
      acc[i][g] = z;
    }

  // prologue: stage iter 0 into buffer 0
#pragma unroll
  for (int s = 0; s < 8; ++s)
    __builtin_amdgcn_global_load_lds(AS1(ptr[s]), AS3(lds + dst[s]), 16, 0, 0);
  __syncthreads();

  for (int it = 0; it < NITER; ++it) {
    const int cur = it & 1;
    const int nxt = cur ^ 1;
    // prefetch iter it+1 into buffers `nxt`
    if (it < NITER - 1) {
      const int koff = (it + 1) * BK;
#pragma unroll
      for (int s = 0; s < 8; ++s)
        __builtin_amdgcn_global_load_lds(AS1(ptr[s] + koff),
                                         AS3(lds + dst[s] + nxt * 16384), 16, 0, 0);
    }
    // compute iter `it` from buffers `cur`
    const char* abuf = lds + cur * 16384;
    const char* bbuf = lds + 32768 + cur * 16384;
#pragma unroll
    for (int t = 0; t < 2; ++t) {
      bf16x8 a[4], b[4];
#pragma unroll
      for (int i = 0; i < 4; ++i) {
        const int row  = wr * 64 + i * 16 + m16;
        const int slot = (t * 4 + quad) ^ (row & 7);
        a[i] = *(const bf16x8*)(abuf + (row * 8 + slot) * 16);
      }
#pragma unroll
      for (int g = 0; g < 4; ++g) {
        const int vr   = g * 32 + wu * 16 + m16;
        const int slot = (t * 4 + quad) ^ (vr & 7);
        b[g] = *(const bf16x8*)(bbuf + (vr * 8 + slot) * 16);
      }
#pragma unroll
      for (int g = 0; g < 4; ++g)
#pragma unroll
        for (int i = 0; i < 4; ++i)
          acc[i][g] = __builtin_amdgcn_mfma_f32_16x16x32_bf16(a[i], b[g], acc[i][g], 0, 0, 0);
    }
    __syncthreads();   // drains prefetch writes + fences reads of `cur`
  }

  // fused LSTM epilogue -- all 4 gates in-lane
  const int u = u0 + wu * 16 + m16;
#pragma unroll
  for (int i = 0; i < 4; ++i)
#pragma unroll
    for (int reg = 0; reg < 4; ++reg) {
      const int r = m0 + wr * 64 + i * 16 + quad * 4 + reg;
      const float z0 = acc[i][0][reg];   // gate i
      const float z1 = acc[i][1][reg];   // gate f
      const float z2 = acc[i][2][reg];   // c_tilde
      const float z3 = acc[i][3][reg];   // gate o
      const float ig = 1.f / (1.f + __expf(-z0));
      const float fg = 1.f / (1.f + __expf(-z1));
      const float ct = 1.f - 2.f / (__expf(2.f * z2) + 1.f);   // tanh, inf-safe
      const float og = 1.f / (1.f + __expf(-z3));
      const float cc = fg * c_tm1[(size_t)r * UNITS + u] + ig * ct;
      const float hh = og * (1.f - 2.f / (__expf(2.f * cc) + 1.f));
      out[(size_t)r * UNITS + u] = hh;
      out[(size_t)BATCH * UNITS + (size_t)r * UNITS + u] = cc;
    }
}

// ---------------------------------------------------------------------------
// Fallback (only if d_ws too small): naive fp32, correct but slow.
// ---------------------------------------------------------------------------
__global__ __launch_bounds__(256) void lstm_naive(
    const float* __restrict__ x, const float* __restrict__ h,
    const float* __restrict__ c_tm1, const float* __restrict__ W,
    float* __restrict__ out) {
  int idx = blockIdx.x * 256 + threadIdx.x;
  int r = idx / UNITS;
  int u = idx % UNITS;
  float z[4] = {0.f, 0.f, 0.f, 0.f};
  for (int k = 0; k < KTOT; ++k) {
    float a = (k < UNITS) ? h[(size_t)r * UNITS + k] : x[(size_t)r * IDIM + k - UNITS];
#pragma unroll
    for (int g = 0; g < 4; ++g)
      z[g] += a * W[(size_t)k * NGATE + g * UNITS + u];
  }
  float ig = 1.f / (1.f + __expf(-z[0]));
  float fg = 1.f / (1.f + __expf(-z[1]));
  float ct = 1.f - 2.f / (__expf(2.f * z[2]) + 1.f);
  float og = 1.f / (1.f + __expf(-z[3]));
  float cc = fg * c_tm1[(size_t)r * UNITS + u] + ig * ct;
  float hh = og * (1.f - 2.f / (__expf(2.f * cc) + 1.f));
  out[(size_t)r * UNITS + u] = hh;
  out[(size_t)BATCH * UNITS + (size_t)r * UNITS + u] = cc;
}

extern "C" void kernel_launch(void* const* d_in, const int* in_sizes, int n_in,
                              void* d_out, int out_size, void* d_ws, size_t ws_size,
                              hipStream_t stream) {
  const float* x = (const float*)d_in[0];   // [2048][512]
  const float* h = (const float*)d_in[1];   // [2048][1024]
  const float* c = (const float*)d_in[2];   // [2048][1024]
  const float* W = (const float*)d_in[3];   // [1536][4096]
  float* out = (float*)d_out;               // h then c, 2 x [2048][1024]

  const size_t needA  = (size_t)BATCH * KTOT * sizeof(__hip_bfloat16);  // 6.29 MB
  const size_t needWt = (size_t)NGATE * KTOT * sizeof(__hip_bfloat16);  // 12.58 MB
  if (ws_size < needA + needWt) {
    hipLaunchKernelGGL(lstm_naive, dim3((BATCH * UNITS) / 256), dim3(256), 0, stream,
                       x, h, c, W, out);
    return;
  }

  __hip_bfloat16* A  = (__hip_bfloat16*)d_ws;
  __hip_bfloat16* Wt = (__hip_bfloat16*)((char*)d_ws + needA);

  hipLaunchKernelGGL(prep, dim3(NBLK_A + NBLK_T), dim3(256), 0, stream, x, h, W, A, Wt);
  hipLaunchKernelGGL(lstm_gemm, dim3(512), dim3(256), 0, stream, A, Wt, c, out);
}